// Round 3
// baseline (353.379 us; speedup 1.0000x reference)
//
#include <hip/hip_runtime.h>
#include <hip/hip_cooperative_groups.h>
#include <math.h>

namespace cg = cooperative_groups;

#define NB    16
#define NPTS  2048
#define NROW  (NB * NPTS)
#define CHUNK 128
#define NCH   16      // NPTS / CHUNK
#define LPAD  132     // CHUNK + 4, LDS transpose pitch (float4-aligned, conflict-light)

struct KArgs {
    const float *x;
    const float *fc1_w, *fc1_b, *bn1_g, *bn1_b;
    const float *fc2_w, *fc2_b, *bn2_g, *bn2_b;
    const float *fc3_w, *fc3_b;
    const float *uw0, *ub0, *ps0, *ph0, *wr0;
    const float *uw1, *ub1, *ps1, *ph1, *wr1;
    const float *uw2, *ub2, *ps2, *ph2, *wr2;
    const float *uw3, *ub3, *ps3, *ph3, *wr3;
    const float *fc4_w, *fc4_b, *bn4_g, *bn4_b;
    const float *fc5_w, *fc5_b, *fc6_w, *fc6_b, *fc7_w, *fc7_b;
    float2 *G;            // [NROW] bn4 stat partials
    float  *Pa, *Pb;      // [256*144] M partial ping-pong
    float  *out;
};

// 144 dot products of length CHUNK over the block's LDS-transposed rows.
__device__ __forceinline__ void block_dots(const float* xT, const float* uT,
                                           int tid, float* __restrict__ Pout, int blk)
{
    for (int k = tid; k < 144; k += CHUNK) {
        const int d = k / 12, e = k - d * 12;
        const float4* xp = (const float4*)(xT + d * LPAD);
        const float4* up = (const float4*)(uT + e * LPAD);
        float m = 0.f;
#pragma unroll
        for (int r = 0; r < CHUNK / 4; ++r) {
            float4 A = xp[r], C = up[r];
            m = fmaf(A.x, C.x, m); m = fmaf(A.y, C.y, m);
            m = fmaf(A.z, C.z, m); m = fmaf(A.w, C.w, m);
        }
        Pout[blk * 144 + k] = m;
    }
}

__global__ __launch_bounds__(128) void fused_all(KArgs a)
{
    __shared__ float w1[18], b1[6], w2[72], b2[12], w3[144], b3[12];
    __shared__ float Wu[4][144], Bu[4][12];
    __shared__ float w4[72], b4[6], w5[18], b5[3], w6[3], w7[6], hb[3];
    __shared__ float xT[12 * LPAD], uT[12 * LPAD], Ml[144];

    const int tid   = threadIdx.x;
    const int blk   = blockIdx.x;
    const int batch = blk >> 4, ch = blk & 15;
    const int n     = ch * CHUNK + tid;          // 0..2047
    const int gRow  = batch * NPTS + n;

    // ---- weights -> LDS (once)
    for (int k = tid; k < 144; k += 128) {
        w3[k] = a.fc3_w[k];
        Wu[0][k] = a.uw0[k]; Wu[1][k] = a.uw1[k];
        Wu[2][k] = a.uw2[k]; Wu[3][k] = a.uw3[k];
    }
    if (tid < 18) { w1[tid] = a.fc1_w[tid]; w5[tid] = a.fc5_w[tid]; }
    if (tid < 6)  { b1[tid] = a.fc1_b[tid]; b4[tid] = a.fc4_b[tid]; w7[tid] = a.fc7_w[tid]; }
    if (tid < 72) { w2[tid] = a.fc2_w[tid]; w4[tid] = a.fc4_w[tid]; }
    if (tid < 12) {
        b2[tid] = a.fc2_b[tid]; b3[tid] = a.fc3_b[tid];
        Bu[0][tid] = a.ub0[tid]; Bu[1][tid] = a.ub1[tid];
        Bu[2][tid] = a.ub2[tid]; Bu[3][tid] = a.ub3[tid];
    }
    if (tid < 3)  { b5[tid] = a.fc5_b[tid]; w6[tid] = a.fc6_w[tid]; }
    if (tid == 0) { hb[0] = a.fc6_b[0]; hb[1] = a.fc7_b[0]; hb[2] = a.fc7_b[1]; }
    __syncthreads();

    cg::grid_group grid = cg::this_grid();

    // =====================================================================
    // P0: encoder. bn1/bn2 stats computed REDUNDANTLY per thread over all
    // 16 batches of this n (no sync needed); own row -> registers.
    // =====================================================================
    float xs0[NB], xs1[NB], xs2[NB];
#pragma unroll
    for (int bb = 0; bb < NB; ++bb) {
        const float* xp = a.x + (bb * NPTS + n) * 3;
        xs0[bb] = xp[0]; xs1[bb] = xp[1]; xs2[bb] = xp[2];
    }
    // bn1 stats over (b,c): 96 vals
    float s = 0.f, q = 0.f;
#pragma unroll
    for (int bb = 0; bb < NB; ++bb)
#pragma unroll
        for (int c = 0; c < 6; ++c) {
            float h = fmaf(w1[c*3], xs0[bb], fmaf(w1[c*3+1], xs1[bb], fmaf(w1[c*3+2], xs2[bb], b1[c])));
            s += h; q = fmaf(h, h, q);
        }
    const float m1 = s * (1.f/96.f);
    const float i1 = 1.f / sqrtf(q*(1.f/96.f) - m1*m1 + 1e-5f);
    const float g1 = a.bn1_g[n] * i1, e1 = a.bn1_b[n];

    // bn2 stats over (b,c): 192 vals; capture own h2 on the fly
    float h2o[12];
    s = 0.f; q = 0.f;
#pragma unroll
    for (int bb = 0; bb < NB; ++bb) {
        float a1v[6];
#pragma unroll
        for (int c = 0; c < 6; ++c) {
            float h = fmaf(w1[c*3], xs0[bb], fmaf(w1[c*3+1], xs1[bb], fmaf(w1[c*3+2], xs2[bb], b1[c])));
            a1v[c] = fmaxf(fmaf(h - m1, g1, e1), 0.f);
        }
#pragma unroll
        for (int c = 0; c < 12; ++c) {
            float h = b2[c];
#pragma unroll
            for (int d = 0; d < 6; ++d) h = fmaf(w2[c*6+d], a1v[d], h);
            s += h; q = fmaf(h, h, q);
            if (bb == batch) h2o[c] = h;
        }
    }
    const float m2 = s * (1.f/192.f);
    const float i2 = 1.f / sqrtf(q*(1.f/192.f) - m2*m2 + 1e-5f);
    const float g2 = a.bn2_g[n] * i2, e2 = a.bn2_b[n];

    float a2[12];
#pragma unroll
    for (int c = 0; c < 12; ++c) a2[c] = fmaxf(fmaf(h2o[c] - m2, g2, e2), 0.f);

    float row[12];
#pragma unroll
    for (int c = 0; c < 12; ++c) {
        float h = b3[c];
#pragma unroll
        for (int d = 0; d < 12; ++d) h = fmaf(w3[c*12+d], a2[d], h);
        row[c] = 1.f / (1.f + expf(-h));
    }

    // M1 partials for this chunk
    {
        float u[12];
#pragma unroll
        for (int k = 0; k < 12; ++k) {
            float acc = Bu[0][k];
#pragma unroll
            for (int d = 0; d < 12; ++d) acc = fmaf(Wu[0][k*12+d], row[d], acc);
            u[k] = fmaxf(acc, 0.f);
        }
#pragma unroll
        for (int k = 0; k < 12; ++k) { xT[k*LPAD + tid] = row[k]; uT[k*LPAD + tid] = u[k]; }
        __syncthreads();
        block_dots(xT, uT, tid, a.Pa, blk);
    }
    grid.sync();   // M1 partials visible

    // =====================================================================
    // relmod 1..3: apply from Pin, produce next-M partials into Pout
    // =====================================================================
#pragma unroll
    for (int r = 0; r < 3; ++r) {
        const float* Pin  = (r == 1) ? a.Pb : a.Pa;   // r=0:Pa, r=1:Pb, r=2:Pa
        float*       Pout = (r == 1) ? a.Pa : a.Pb;
        const float* psp = (r == 0) ? a.ps0 : (r == 1) ? a.ps1 : a.ps2;
        const float* php = (r == 0) ? a.ph0 : (r == 1) ? a.ph1 : a.ph2;
        const float* wrp = (r == 0) ? a.wr0 : (r == 1) ? a.wr1 : a.wr2;
        const float coef = wrp[0] * psp[0] * php[0] * (1.f / (float)NPTS);

        for (int k = tid; k < 144; k += 128) {
            float sm = 0.f;
#pragma unroll
            for (int c = 0; c < NCH; ++c) sm += Pin[(batch * NCH + c) * 144 + k];
            Ml[k] = sm;
        }
        __syncthreads();

        float u[12];
#pragma unroll
        for (int k = 0; k < 12; ++k) {
            float acc = Bu[r][k];
#pragma unroll
            for (int d = 0; d < 12; ++d) acc = fmaf(Wu[r][k*12+d], row[d], acc);
            u[k] = fmaxf(acc, 0.f);
        }
        float xx = 0.f;
#pragma unroll
        for (int d = 0; d < 12; ++d) xx = fmaf(row[d], row[d], xx);
        float fo[12];
#pragma unroll
        for (int e = 0; e < 12; ++e) {
            float acc = 0.f;
#pragma unroll
            for (int d = 0; d < 12; ++d) acc = fmaf(row[d], Ml[d*12+e], acc);
            fo[e] = fmaf(coef, fmaf(-xx, u[e], acc), row[e]);
        }
#pragma unroll
        for (int d = 0; d < 12; ++d) row[d] = fo[d];

        // next relmod's unary + partials
        float un[12];
#pragma unroll
        for (int k = 0; k < 12; ++k) {
            float acc = Bu[r+1][k];
#pragma unroll
            for (int d = 0; d < 12; ++d) acc = fmaf(Wu[r+1][k*12+d], row[d], acc);
            un[k] = fmaxf(acc, 0.f);
        }
        __syncthreads();   // all lanes done reading Ml/xT before overwrite
#pragma unroll
        for (int k = 0; k < 12; ++k) { xT[k*LPAD + tid] = row[k]; uT[k*LPAD + tid] = un[k]; }
        __syncthreads();
        block_dots(xT, uT, tid, Pout, blk);
        grid.sync();
    }

    // =====================================================================
    // relmod 4 apply (Pin = Pb) + fc4 -> bn4 stat partials
    // =====================================================================
    float h4[6];
    {
        for (int k = tid; k < 144; k += 128) {
            float sm = 0.f;
#pragma unroll
            for (int c = 0; c < NCH; ++c) sm += a.Pb[(batch * NCH + c) * 144 + k];
            Ml[k] = sm;
        }
        __syncthreads();
        const float coef = a.wr3[0] * a.ps3[0] * a.ph3[0] * (1.f / (float)NPTS);
        float u[12];
#pragma unroll
        for (int k = 0; k < 12; ++k) {
            float acc = Bu[3][k];
#pragma unroll
            for (int d = 0; d < 12; ++d) acc = fmaf(Wu[3][k*12+d], row[d], acc);
            u[k] = fmaxf(acc, 0.f);
        }
        float xx = 0.f;
#pragma unroll
        for (int d = 0; d < 12; ++d) xx = fmaf(row[d], row[d], xx);
        float fo[12];
#pragma unroll
        for (int e = 0; e < 12; ++e) {
            float acc = 0.f;
#pragma unroll
            for (int d = 0; d < 12; ++d) acc = fmaf(row[d], Ml[d*12+e], acc);
            fo[e] = fmaf(coef, fmaf(-xx, u[e], acc), row[e]);
        }
#pragma unroll
        for (int d = 0; d < 12; ++d) row[d] = fo[d];

        float ss = 0.f, qq = 0.f;
#pragma unroll
        for (int c = 0; c < 6; ++c) {
            float h = b4[c];
#pragma unroll
            for (int d = 0; d < 12; ++d) h = fmaf(w4[c*12+d], row[d], h);
            h4[c] = h; ss += h; qq = fmaf(h, h, qq);
        }
        a.G[gRow] = make_float2(ss, qq);
    }
    grid.sync();   // bn4 partials visible

    // =====================================================================
    // final: bn4 + fc5 + heads
    // =====================================================================
    s = 0.f; q = 0.f;
#pragma unroll
    for (int bb = 0; bb < NB; ++bb) { float2 t = a.G[bb * NPTS + n]; s += t.x; q += t.y; }
    const float m4 = s * (1.f/96.f);
    const float i4 = 1.f / sqrtf(q*(1.f/96.f) - m4*m4 + 1e-5f);
    const float g4 = a.bn4_g[n] * i4, e4 = a.bn4_b[n];
    float a4[6];
#pragma unroll
    for (int c = 0; c < 6; ++c) a4[c] = fmaxf(fmaf(h4[c] - m4, g4, e4), 0.f);

    float a5[3];
#pragma unroll
    for (int c = 0; c < 3; ++c) {
        float h = b5[c];
#pragma unroll
        for (int d = 0; d < 6; ++d) h = fmaf(w5[c*6+d], a4[d], h);
        a5[c] = fmaxf(h, 0.f);
    }
    const float cls = fmaf(w6[0], a5[0], fmaf(w6[1], a5[1], fmaf(w6[2], a5[2], hb[0])));
    const float g0  = fmaf(w7[0], a5[0], fmaf(w7[1], a5[1], fmaf(w7[2], a5[2], hb[1])));
    const float g1v = fmaf(w7[3], a5[0], fmaf(w7[4], a5[1], fmaf(w7[5], a5[2], hb[2])));
    float* op = a.out + gRow * 3;
    op[0] = cls; op[1] = g0; op[2] = g1v;
}

// ---------------------------------------------------------------------------
extern "C" void kernel_launch(void* const* d_in, const int* in_sizes, int n_in,
                              void* d_out, int out_size, void* d_ws, size_t ws_size,
                              hipStream_t stream)
{
    KArgs ka;
    ka.x     = (const float*)d_in[0];
    ka.fc1_w = (const float*)d_in[1];  ka.fc1_b = (const float*)d_in[2];
    ka.bn1_g = (const float*)d_in[3];  ka.bn1_b = (const float*)d_in[4];
    ka.fc2_w = (const float*)d_in[5];  ka.fc2_b = (const float*)d_in[6];
    ka.bn2_g = (const float*)d_in[7];  ka.bn2_b = (const float*)d_in[8];
    ka.fc3_w = (const float*)d_in[9];  ka.fc3_b = (const float*)d_in[10];
    ka.uw0 = (const float*)d_in[11]; ka.ub0 = (const float*)d_in[12];
    ka.ps0 = (const float*)d_in[13]; ka.ph0 = (const float*)d_in[14]; ka.wr0 = (const float*)d_in[15];
    ka.uw1 = (const float*)d_in[16]; ka.ub1 = (const float*)d_in[17];
    ka.ps1 = (const float*)d_in[18]; ka.ph1 = (const float*)d_in[19]; ka.wr1 = (const float*)d_in[20];
    ka.uw2 = (const float*)d_in[21]; ka.ub2 = (const float*)d_in[22];
    ka.ps2 = (const float*)d_in[23]; ka.ph2 = (const float*)d_in[24]; ka.wr2 = (const float*)d_in[25];
    ka.uw3 = (const float*)d_in[26]; ka.ub3 = (const float*)d_in[27];
    ka.ps3 = (const float*)d_in[28]; ka.ph3 = (const float*)d_in[29]; ka.wr3 = (const float*)d_in[30];
    ka.fc4_w = (const float*)d_in[31]; ka.fc4_b = (const float*)d_in[32];
    ka.bn4_g = (const float*)d_in[33]; ka.bn4_b = (const float*)d_in[34];
    ka.fc5_w = (const float*)d_in[35]; ka.fc5_b = (const float*)d_in[36];
    ka.fc6_w = (const float*)d_in[37]; ka.fc6_b = (const float*)d_in[38];
    ka.fc7_w = (const float*)d_in[39]; ka.fc7_b = (const float*)d_in[40];

    float* ws = (float*)d_ws;
    ka.G  = (float2*)ws;                 // 32768 float2  = 65536 floats
    ka.Pa = ws + 65536;                  // 256*144 = 36864
    ka.Pb = ws + 65536 + 36864;
    ka.out = (float*)d_out;

    void* args[] = { &ka };
    hipLaunchCooperativeKernel((void*)fused_all, dim3(NB * NCH), dim3(CHUNK),
                               args, 0, stream);
}